// Round 1
// baseline (241.358 us; speedup 1.0000x reference)
//
#include <hip/hip_runtime.h>
#include <math.h>

#pragma clang fp contract(off)

#define NB 16
#define NC 80
#define NTOT 17064
#define TOPK 1000
#define NBINS 8192
#define CAP 4096
#define MAXDET 100
#define CNTSTRIDE 64     // u32 stride between per-batch counters = 256 B
#define CHUNK 128        // NMS staging chunk
#define GH 128           // hist/compact blocks per batch
#define SEGCAP 768       // per-block candidate segment (avg ~128, 6x headroom)
#define FB 16            // filter blocks per batch (GH % FB == 0)

struct Ptrs {
    const float* lg[5];
    const float* bb[5];
    const float* ct[5];
};

__device__ __forceinline__ void level_of(int n, int& l, int& hw, int& W,
                                         int& stride, int& half, int& HW) {
    if (n < 12800)      { l = 0; hw = n;         W = 128; stride = 8;   half = 4;  HW = 12800; }
    else if (n < 16000) { l = 1; hw = n - 12800; W = 64;  stride = 16;  half = 8;  HW = 3200;  }
    else if (n < 16800) { l = 2; hw = n - 16000; W = 32;  stride = 32;  half = 16; HW = 800;   }
    else if (n < 17008) { l = 3; hw = n - 16800; W = 16;  stride = 64;  half = 32; HW = 208;   }
    else                { l = 4; hw = n - 17008; W = 8;   stride = 128; half = 64; HW = 56;    }
}

// Fast HW sigmoid (v_exp_f32 + v_rcp_f32). |fast - exact| <= ~15 ulp on the
// comb product. Used for gating/binning only; keys are always exact.
__device__ __forceinline__ float fast_sig(float x) {
    float e = __expf(-x);
    return __builtin_amdgcn_rcpf(1.0f + e);
}

// ---------------- pass 1: gated 64-bin histogram + candidate store ----------
// Gate: fast comb bits >= bits(0.08)-64. In-gate => exact cls >= exact comb
// >= 0.0798 > 0.05. Conservative local bin lb = ((bits-32)>>19)-BINBASE: any
// element whose conservative bin is >= BINBASE+1 has bits >= gate AND
// x > -2.45 > -2.47 => counted AND STORED. So for T >= BINBASE+1 (guaranteed
// by k_filter's ok-check), {exact bin >= T} is a subset of the stored set:
// exact bits >= (T<<19) => fast bits >= (T<<19)-64 > bits(0.08)-64 = FB_LO.
// Stored entries go to per-BLOCK segments with an LDS counter -> no global
// counter needs pre-zeroing (blkcnt is plain-stored unconditionally at end).
#define HG_ELEM(X, CT, J, CC, NB0)                                            \
    if ((X) > -2.47f) {                   /* logit(0.08) = -2.442 */          \
        float cls = fast_sig(X);                                              \
        float cen = fast_sig(CT);                                             \
        unsigned bits = __float_as_uint(cls * cen);                           \
        if (bits >= FB_LO) {                                                  \
            int lb = (int)((bits - 32u) >> 19) - BINBASE;                     \
            lb = (lb < 0) ? 0 : ((lb > 63) ? 63 : lb);                        \
            atomicAdd(&whv[lb], 1u);                                          \
            unsigned pos = atomicAdd(s_na, 1u);                               \
            if (pos < SEGCAP) {                                               \
                unsigned idx = (unsigned)(((NB0) + (J)) * NC + (CC));         \
                segb[pos] = ((unsigned long long)bits << 32) | idx;           \
            }                                                                 \
        }                                                                     \
    }

template<int HW4, int NF4, int LVOFF>
__device__ __forceinline__ void histg_level(const float* lgb, const float* ctb,
        int tid, int bx, int gx, unsigned FB_LO, int BINBASE, unsigned* whv,
        unsigned* s_na, unsigned long long* segb) {
    for (int i0 = bx * 512; i0 < NF4; i0 += gx * 512) {
        int ia = i0 + tid, ib = i0 + 256 + tid;
        bool la = ia < NF4, lb2 = ib < NF4;
        float4 va = make_float4(-9.f, -9.f, -9.f, -9.f);
        float4 vb = make_float4(-9.f, -9.f, -9.f, -9.f);
        int hwa = 0, hwb = 0, cca = 0, ccb = 0;
        if (la) {
            cca = ia / HW4; hwa = ia - cca * HW4;
            va = *(const float4*)(lgb + cca * (HW4 * 4) + hwa * 4);
        }
        if (lb2) {
            ccb = ib / HW4; hwb = ib - ccb * HW4;
            vb = *(const float4*)(lgb + ccb * (HW4 * 4) + hwb * 4);
        }
        if (va.x > -2.47f || va.y > -2.47f || va.z > -2.47f || va.w > -2.47f) {
            float4 cv = *(const float4*)(ctb + hwa * 4);
            int nb0 = LVOFF + hwa * 4;
            HG_ELEM(va.x, cv.x, 0, cca, nb0) HG_ELEM(va.y, cv.y, 1, cca, nb0)
            HG_ELEM(va.z, cv.z, 2, cca, nb0) HG_ELEM(va.w, cv.w, 3, cca, nb0)
        }
        if (vb.x > -2.47f || vb.y > -2.47f || vb.z > -2.47f || vb.w > -2.47f) {
            float4 cv = *(const float4*)(ctb + hwb * 4);
            int nb0 = LVOFF + hwb * 4;
            HG_ELEM(vb.x, cv.x, 0, ccb, nb0) HG_ELEM(vb.y, cv.y, 1, ccb, nb0)
            HG_ELEM(vb.z, cv.z, 2, ccb, nb0) HG_ELEM(vb.w, cv.w, 3, ccb, nb0)
        }
    }
}
#undef HG_ELEM

__global__ void __launch_bounds__(256) k_histB(Ptrs p, unsigned* hist, unsigned* cnt2,
                                               unsigned* blkcnt, unsigned long long* segs) {
    __shared__ unsigned wh[4][64];   // per-wave 64-bin hist, 1 KiB
    __shared__ unsigned s_na;        // block-local candidate count
    int b = blockIdx.y, tid = threadIdx.x, bx = blockIdx.x, gx = gridDim.x;
    int wv = tid >> 6;
    if (bx == 0 && tid == 0) cnt2[(size_t)b * CNTSTRIDE] = 0;   // replaces memset
    ((unsigned*)wh)[tid] = 0;        // 256 == 4*64
    if (tid == 0) s_na = 0;
    __syncthreads();
    unsigned FB_LO = __float_as_uint(0.08f) - 64u;
    int BINBASE = (int)(__float_as_uint(0.08f) >> 19);
    unsigned* whv = wh[wv];
    unsigned long long* segb = segs + ((size_t)b * GH + bx) * SEGCAP;

    histg_level<3200, 256000,     0>(p.lg[0] + (size_t)b * NC * 12800, p.ct[0] + (size_t)b * 12800, tid, bx, gx, FB_LO, BINBASE, whv, &s_na, segb);
    histg_level< 800,  64000, 12800>(p.lg[1] + (size_t)b * NC * 3200,  p.ct[1] + (size_t)b * 3200,  tid, bx, gx, FB_LO, BINBASE, whv, &s_na, segb);
    histg_level< 200,  16000, 16000>(p.lg[2] + (size_t)b * NC * 800,   p.ct[2] + (size_t)b * 800,   tid, bx, gx, FB_LO, BINBASE, whv, &s_na, segb);
    histg_level<  52,   4160, 16800>(p.lg[3] + (size_t)b * NC * 208,   p.ct[3] + (size_t)b * 208,   tid, bx, gx, FB_LO, BINBASE, whv, &s_na, segb);
    histg_level<  14,   1120, 17008>(p.lg[4] + (size_t)b * NC * 56,    p.ct[4] + (size_t)b * 56,    tid, bx, gx, FB_LO, BINBASE, whv, &s_na, segb);

    __syncthreads();
    if (tid < 64) {                  // per-block private slot: plain store, no atomics
        unsigned s = wh[0][tid] + wh[1][tid] + wh[2][tid] + wh[3][tid];
        hist[((size_t)b * GH + bx) * 64 + tid] = s;
    }
    if (tid == 0) blkcnt[(size_t)b * GH + bx] = s_na;   // raw count (may exceed SEGCAP)
}

// Fallback full-population conservative histogram (round-9 semantics; only
// runs if the gated ok-check fails — never for this data).
template<int HW4, int NF4>
__device__ __forceinline__ void histf_level(const float* lgb, const float* ctb,
                                            int tid, unsigned* hist) {
    for (int i0 = 0; i0 < NF4; i0 += 256) {
        int i = i0 + tid;
        if (i < NF4) {
            int c = i / HW4, hwf = i - c * HW4;
            float4 v = *(const float4*)(lgb + c * (HW4 * 4) + hwf * 4);
            if (v.x > -2.95f || v.y > -2.95f || v.z > -2.95f || v.w > -2.95f) {
                float4 cv = *(const float4*)(ctb + hwf * 4);
                float xs[4] = {v.x, v.y, v.z, v.w};
                float cs[4] = {cv.x, cv.y, cv.z, cv.w};
#pragma unroll
                for (int j = 0; j < 4; ++j) {
                    float x = xs[j];
                    if (x > -2.95f) {
                        float cls = fast_sig(x);
                        if (cls > 0.04999f) {
                            bool in = true;
                            if (cls < 0.05001f)
                                in = (1.0f / (1.0f + expf(-x))) > 0.05f;
                            if (in) {
                                float cen = fast_sig(cs[j]);
                                unsigned bits = __float_as_uint(cls * cen);
                                unsigned cb = (bits > 32u) ? bits - 32u : 0u;
                                atomicAdd(&hist[cb >> 19], 1u);
                            }
                        }
                    }
                }
            }
        }
    }
}

// ---------------- fallback full re-read compact (never taken for this data) -
#define CD_J(J, X, CT, NB0, CC, F, K)                                         \
    if ((X) > xpre) {                                                         \
        float cls = 1.0f / (1.0f + expf(-(X)));                               \
        if (cls > 0.05f) {                                                    \
            float cen = 1.0f / (1.0f + expf(-(CT)));                          \
            float comb = cls * cen;                                           \
            unsigned bits = __float_as_uint(comb);                            \
            if ((bits >> 19) >= Tb) {                                         \
                unsigned idx = (unsigned)(((NB0) + (J)) * NC + (CC));         \
                K = ((unsigned long long)bits << 32) | (0xFFFFFFFFu - idx);   \
                F = true;                                                     \
            }                                                                 \
        }                                                                     \
    }

template<int HW4, int NF4, int LVOFF>
__device__ __forceinline__ void compact_level(const float* lgb, const float* ctb,
        int tid, int lane, int bx, int gx, unsigned Tb, float xpre,
        unsigned* cntb, unsigned long long* selb, unsigned long long ltmask) {
    for (int i0 = bx * 512; i0 < NF4; i0 += gx * 512) {
        int ia = i0 + tid, ib2 = i0 + 256 + tid;
        bool la = ia < NF4, lb2 = ib2 < NF4;
        float4 va = make_float4(-9.f, -9.f, -9.f, -9.f);
        float4 vb = make_float4(-9.f, -9.f, -9.f, -9.f);
        int hwa = 0, hwb = 0, cca = 0, ccb = 0;
        if (la) {
            cca = ia / HW4; hwa = ia - cca * HW4;
            va = *(const float4*)(lgb + cca * (HW4 * 4) + hwa * 4);
        }
        if (lb2) {
            ccb = ib2 / HW4; hwb = ib2 - ccb * HW4;
            vb = *(const float4*)(lgb + ccb * (HW4 * 4) + hwb * 4);
        }
        {
            bool f0 = false, f1 = false, f2 = false, f3 = false;
            unsigned long long k0 = 0, k1 = 0, k2 = 0, k3 = 0;
            if (va.x > xpre || va.y > xpre || va.z > xpre || va.w > xpre) {
                float4 cv = *(const float4*)(ctb + hwa * 4);
                int nb0 = LVOFF + hwa * 4;
                CD_J(0, va.x, cv.x, nb0, cca, f0, k0)
                CD_J(1, va.y, cv.y, nb0, cca, f1, k1)
                CD_J(2, va.z, cv.z, nb0, cca, f2, k2)
                CD_J(3, va.w, cv.w, nb0, cca, f3, k3)
            }
            unsigned long long m0 = __ballot(f0), m1 = __ballot(f1);
            unsigned long long m2 = __ballot(f2), m3 = __ballot(f3);
            if (m0 | m1 | m2 | m3) {
                unsigned t0 = (unsigned)__popcll(m0), t1 = (unsigned)__popcll(m1);
                unsigned t2 = (unsigned)__popcll(m2), t3 = (unsigned)__popcll(m3);
                int basep = 0;
                if (lane == 0) basep = (int)atomicAdd(cntb, t0 + t1 + t2 + t3);
                basep = __shfl(basep, 0);
                if (f0) { int pos = basep + (int)__popcll(m0 & ltmask);                       if (pos < CAP) selb[pos] = k0; }
                if (f1) { int pos = basep + (int)t0 + (int)__popcll(m1 & ltmask);             if (pos < CAP) selb[pos] = k1; }
                if (f2) { int pos = basep + (int)(t0 + t1) + (int)__popcll(m2 & ltmask);      if (pos < CAP) selb[pos] = k2; }
                if (f3) { int pos = basep + (int)(t0 + t1 + t2) + (int)__popcll(m3 & ltmask); if (pos < CAP) selb[pos] = k3; }
            }
        }
        {
            bool f0 = false, f1 = false, f2 = false, f3 = false;
            unsigned long long k0 = 0, k1 = 0, k2 = 0, k3 = 0;
            if (vb.x > xpre || vb.y > xpre || vb.z > xpre || vb.w > xpre) {
                float4 cv = *(const float4*)(ctb + hwb * 4);
                int nb0 = LVOFF + hwb * 4;
                CD_J(0, vb.x, cv.x, nb0, ccb, f0, k0)
                CD_J(1, vb.y, cv.y, nb0, ccb, f1, k1)
                CD_J(2, vb.z, cv.z, nb0, ccb, f2, k2)
                CD_J(3, vb.w, cv.w, nb0, ccb, f3, k3)
            }
            unsigned long long m0 = __ballot(f0), m1 = __ballot(f1);
            unsigned long long m2 = __ballot(f2), m3 = __ballot(f3);
            if (m0 | m1 | m2 | m3) {
                unsigned t0 = (unsigned)__popcll(m0), t1 = (unsigned)__popcll(m1);
                unsigned t2 = (unsigned)__popcll(m2), t3 = (unsigned)__popcll(m3);
                int basep = 0;
                if (lane == 0) basep = (int)atomicAdd(cntb, t0 + t1 + t2 + t3);
                basep = __shfl(basep, 0);
                if (f0) { int pos = basep + (int)__popcll(m0 & ltmask);                       if (pos < CAP) selb[pos] = k0; }
                if (f1) { int pos = basep + (int)t0 + (int)__popcll(m1 & ltmask);             if (pos < CAP) selb[pos] = k1; }
                if (f2) { int pos = basep + (int)(t0 + t1) + (int)__popcll(m2 & ltmask);      if (pos < CAP) selb[pos] = k2; }
                if (f3) { int pos = basep + (int)(t0 + t1 + t2) + (int)__popcll(m3 & ltmask); if (pos < CAP) selb[pos] = k3; }
            }
        }
    }
}
#undef CD_J

__device__ __forceinline__ void run_compact(const Ptrs& p, int b, int tid, int lane,
        int bx, int gx, unsigned Tb, unsigned* cnt2, unsigned long long* sel) {
    float mthr = __uint_as_float(Tb << 19);
    float xpre = -2.95f;
    if (mthr > 1e-37f && mthr < 1.0f) {
        float lm = logf(mthr / (1.0f - mthr)) - 0.01f;
        if (lm > xpre) xpre = lm;
    }
    unsigned long long ltmask = (1ULL << lane) - 1ULL;
    unsigned* cntb = cnt2 + (size_t)b * CNTSTRIDE;
    unsigned long long* selb = sel + (size_t)b * CAP;
    compact_level<3200, 256000,     0>(p.lg[0] + (size_t)b * NC * 12800, p.ct[0] + (size_t)b * 12800, tid, lane, bx, gx, Tb, xpre, cntb, selb, ltmask);
    compact_level< 800,  64000, 12800>(p.lg[1] + (size_t)b * NC * 3200,  p.ct[1] + (size_t)b * 3200,  tid, lane, bx, gx, Tb, xpre, cntb, selb, ltmask);
    compact_level< 200,  16000, 16000>(p.lg[2] + (size_t)b * NC * 800,   p.ct[2] + (size_t)b * 800,   tid, lane, bx, gx, Tb, xpre, cntb, selb, ltmask);
    compact_level<  52,   4160, 16800>(p.lg[3] + (size_t)b * NC * 208,   p.ct[3] + (size_t)b * 208,   tid, lane, bx, gx, Tb, xpre, cntb, selb, ltmask);
    compact_level<  14,   1120, 17008>(p.lg[4] + (size_t)b * NC * 56,    p.ct[4] + (size_t)b * 56,    tid, lane, bx, gx, Tb, xpre, cntb, selb, ltmask);
}

// ---------------- pass 2: threshold + filter stored candidates --------------
// Fast path: compute T from the coarse hist (as old k_thresh), then re-read
// ONLY the stored (fastbits,idx) candidates, recompute EXACT keys for those
// with fastbits >= (T<<19)-64 (conservative superset of exact bin >= T), and
// append exact-bin>=T survivors to sel. Eliminates the 87 MB logits re-read.
// Fallbacks (never taken for this data): !ok -> fine full-pop histogram + full
// re-read by block 0; segment overflow -> full re-read by all FB blocks.
__global__ void __launch_bounds__(256) k_filter(Ptrs p, const unsigned* hist,
        const unsigned* blkcnt, const unsigned long long* segs,
        unsigned* cnt2, unsigned long long* sel) {
    __shared__ unsigned part[4][64];
    __shared__ unsigned red[64];
    __shared__ unsigned fullh[NBINS];   // fallback only (32 KiB)
    __shared__ int s_T, s_ok;
    __shared__ unsigned s_ovf;
    int b = blockIdx.y, tid = threadIdx.x, bx = blockIdx.x;
    int bin = tid & 63, grp = tid >> 6, lane = tid & 63;
    int BINBASE = (int)(__float_as_uint(0.08f) >> 19);

    unsigned s = 0;
    for (int blk = grp; blk < GH; blk += 4)
        s += hist[((size_t)b * GH + blk) * 64 + bin];   // coalesced per 64-group
    part[grp][bin] = s;
    if (tid == 0) s_ovf = 0;
    __syncthreads();
    if (tid < 64) red[tid] = part[0][tid] + part[1][tid] + part[2][tid] + part[3][tid];
    unsigned ov = 0;
    for (int i = tid; i < GH; i += 256)
        ov |= (blkcnt[(size_t)b * GH + i] > SEGCAP) ? 1u : 0u;
    if (ov) atomicOr(&s_ovf, 1u);
    __syncthreads();
    if (tid == 0) {
        unsigned suf1 = 0;
        for (int i = 1; i < 64; ++i) suf1 += red[i];
        unsigned run = 0; int Tl = 0;
        for (int i = 63; i >= 1; --i) {
            run += red[i];
            if (run >= TOPK) { Tl = i; break; }
        }
        s_ok = (suf1 >= TOPK);
        s_T = Tl + BINBASE;
    }
    __syncthreads();

    if (s_ok && !s_ovf) {
        unsigned Tb = (unsigned)s_T;
        unsigned FLO = (Tb << 19) - 64u;    // T >= BINBASE+1 => no underflow
        unsigned* cntb = cnt2 + (size_t)b * CNTSTRIDE;
        unsigned long long* selb = sel + (size_t)b * CAP;
        unsigned long long ltmask = (1ULL << lane) - 1ULL;
        for (int sg = bx; sg < GH; sg += FB) {
            unsigned cs = blkcnt[(size_t)b * GH + sg];
            if (cs > SEGCAP) cs = SEGCAP;
            const unsigned long long* sp = segs + ((size_t)b * GH + sg) * SEGCAP;
            for (unsigned e0 = 0; e0 < cs; e0 += 256) {
                unsigned e = e0 + (unsigned)tid;
                bool take = false;
                unsigned long long key = 0;
                if (e < cs) {
                    unsigned long long kk = sp[e];
                    if ((unsigned)(kk >> 32) >= FLO) {
                        unsigned idx = (unsigned)kk;
                        int n = (int)(idx / NC), c = (int)(idx - (unsigned)n * NC);
                        int l, hw, W, stride, half, HW;
                        level_of(n, l, hw, W, stride, half, HW);
                        float x   = p.lg[l][(size_t)b * NC * HW + (size_t)c * HW + hw];
                        float ctv = p.ct[l][(size_t)b * HW + hw];
                        float cls = 1.0f / (1.0f + expf(-x));
                        if (cls > 0.05f) {           // auto-true when bin>=T; kept for safety
                            float cen = 1.0f / (1.0f + expf(-ctv));
                            unsigned bits = __float_as_uint(cls * cen);
                            if ((bits >> 19) >= Tb) {
                                key = ((unsigned long long)bits << 32) | (0xFFFFFFFFu - idx);
                                take = true;
                            }
                        }
                    }
                }
                unsigned long long m = __ballot(take);
                if (m) {
                    unsigned tot = (unsigned)__popcll(m);
                    int basep = 0;
                    if (lane == 0) basep = (int)atomicAdd(cntb, tot);
                    basep = __shfl(basep, 0);
                    if (take) {
                        int pos = basep + (int)__popcll(m & ltmask);
                        if (pos < CAP) selb[pos] = key;
                    }
                }
            }
        }
        return;
    }

    if (!s_ok) {                        // never taken for this data
        if (bx != 0) return;
        for (int i = tid; i < NBINS; i += 256) fullh[i] = 0;
        __syncthreads();
        histf_level<3200, 256000>(p.lg[0] + (size_t)b * NC * 12800, p.ct[0] + (size_t)b * 12800, tid, fullh);
        histf_level< 800,  64000>(p.lg[1] + (size_t)b * NC * 3200,  p.ct[1] + (size_t)b * 3200,  tid, fullh);
        histf_level< 200,  16000>(p.lg[2] + (size_t)b * NC * 800,   p.ct[2] + (size_t)b * 800,   tid, fullh);
        histf_level<  52,   4160>(p.lg[3] + (size_t)b * NC * 208,   p.ct[3] + (size_t)b * 208,   tid, fullh);
        histf_level<  14,   1120>(p.lg[4] + (size_t)b * NC * 56,    p.ct[4] + (size_t)b * 56,    tid, fullh);
        __syncthreads();
        if (tid == 0) {
            unsigned run = 0; int Tf = 0;
            for (int i = NBINS - 1; i >= 0; --i) {
                run += fullh[i];
                if (run >= TOPK) { Tf = i; break; }
            }
            s_T = Tf;
        }
        __syncthreads();
        run_compact(p, b, tid, lane, 0, 1, (unsigned)s_T, cnt2, sel);
        return;
    }

    // ok but segment overflow: T valid, full re-read with FB blocks (never taken)
    run_compact(p, b, tid, lane, bx, FB, (unsigned)s_T, cnt2, sel);
}

// ---------------- rank + decode (distributed across CUs) --------------------
__global__ void __launch_bounds__(256) k_rankdec(Ptrs p, const unsigned* cnt,
                                                 const unsigned long long* sel,
                                                 const float* im_info, float* cand) {
    __shared__ __align__(16) unsigned long long keys[CAP];
    int b = blockIdx.y, tid = threadIdx.x;
    unsigned M = cnt[(size_t)b * CNTSTRIDE];
    if (M > CAP) M = CAP;
    int s0 = blockIdx.x * 256;
    if (s0 >= (int)M) return;
    int Mpad = (int)((M + 1u) & ~1u);
    for (int i = tid; i < Mpad; i += 256)
        keys[i] = (i < (int)M) ? sel[(size_t)b * CAP + i] : 0ULL;
    __syncthreads();

    int s = s0 + tid;
    if (s >= (int)M) return;
    unsigned long long k = keys[s];
    int rank = 0;
    for (int j = 0; j < Mpad; j += 2) {
        ulonglong2 kk = *(const ulonglong2*)&keys[j];   // wave-broadcast b128
        rank += (kk.x > k) ? 1 : 0;
        rank += (kk.y > k) ? 1 : 0;
    }
    if (rank >= TOPK) return;

    float Him = im_info[b * 2 + 0], Wim = im_info[b * 2 + 1];
    float xmax = Wim - 1.0f, ymax = Him - 1.0f;
    unsigned sb = (unsigned)(k >> 32);
    unsigned idx = 0xFFFFFFFFu - (unsigned)(k & 0xFFFFFFFFu);
    float val = __uint_as_float(sb);
    int n = idx / NC, c = idx - n * NC;
    int l, hw, W, stride, half, HW;
    level_of(n, l, hw, W, stride, half, HW);
    int wx = hw % W, hy = hw / W;
    float locx = (float)(wx * stride + half);
    float locy = (float)(hy * stride + half);
    const float* bb = p.bb[l] + (size_t)b * 4 * HW + hw;
    float r0 = bb[0], r1 = bb[(size_t)HW], r2 = bb[(size_t)2 * HW], r3 = bb[(size_t)3 * HW];
    float x1 = locx - r0, y1 = locy - r1, x2 = locx + r2, y2 = locy + r3;
    x1 = fminf(fmaxf(x1, 0.f), xmax);
    y1 = fminf(fmaxf(y1, 0.f), ymax);
    x2 = fminf(fmaxf(x2, 0.f), xmax);
    y2 = fminf(fmaxf(y2, 0.f), ymax);
    float scv = sqrtf(val + 1e-12f);
    float off = (float)c * 10000.0f;
    float a0 = x1 + off, a1 = y1 + off, a2 = x2 + off, a3 = y2 + off;
    float area = fmaxf(a2 - a0, 0.f) * fmaxf(a3 - a1, 0.f);
    float* dst = cand + ((size_t)b * TOPK + rank) * 12;
    *(float4*)(dst + 0) = make_float4(x1, y1, x2, y2);
    *(float4*)(dst + 4) = make_float4(a0, a1, a2, a3);
    *(float4*)(dst + 8) = make_float4(area, scv, (float)c, 0.f);
}

// ---------------- scan-NMS (one wave per batch) -----------------------------
__global__ void __launch_bounds__(64) k_nms(const unsigned* cnt, const float* cand,
                                            float* out) {
    __shared__ float4 s_ob[CHUNK], s_nb[CHUNK], s_ms[CHUNK];
    int b = blockIdx.x, lane = threadIdx.x;
    unsigned M = cnt[(size_t)b * CNTSTRIDE];
    if (M > CAP) M = CAP;
    int ncand = (int)M < TOPK ? (int)M : TOPK;
    const float* src = cand + (size_t)b * TOPK * 12;
    float* ob = out + (size_t)b * MAXDET * 6;

    int na = 0;
    float4 a0b = make_float4(0.f, 0.f, 0.f, 0.f);
    float4 a1b = make_float4(0.f, 0.f, 0.f, 0.f);
    float a0a = 0.f, a1a = 0.f;

    for (int base = 0; base < ncand && na < MAXDET; base += CHUNK) {
        int cn = ncand - base; if (cn > CHUNK) cn = CHUNK;
        for (int cidx = lane; cidx < cn; cidx += 64) {
            const float* s = src + (size_t)(base + cidx) * 12;
            s_ob[cidx] = *(const float4*)(s + 0);
            s_nb[cidx] = *(const float4*)(s + 4);
            s_ms[cidx] = *(const float4*)(s + 8);
        }
        __syncthreads();
        for (int r = 0; r < cn && na < MAXDET; ++r) {
            float4 cb = s_nb[r];
            float ca = s_ms[r].x;
            bool sup = false;
            if (lane < na) {
                float xx1 = fmaxf(a0b.x, cb.x);
                float yy1 = fmaxf(a0b.y, cb.y);
                float xx2 = fminf(a0b.z, cb.z);
                float yy2 = fminf(a0b.w, cb.w);
                float inter = fmaxf(xx2 - xx1, 0.f) * fmaxf(yy2 - yy1, 0.f);
                float iou = inter / (((a0a + ca) - inter) + 1e-9f);
                sup = (iou >= 0.6f);
            }
            if (lane + 64 < na) {
                float xx1 = fmaxf(a1b.x, cb.x);
                float yy1 = fmaxf(a1b.y, cb.y);
                float xx2 = fminf(a1b.z, cb.z);
                float yy2 = fminf(a1b.w, cb.w);
                float inter = fmaxf(xx2 - xx1, 0.f) * fmaxf(yy2 - yy1, 0.f);
                float iou = inter / (((a1a + ca) - inter) + 1e-9f);
                sup |= (iou >= 0.6f);
            }
            if (__ballot(sup) == 0ULL) {
                if (lane == (na & 63)) {
                    if (na < 64) { a0b = cb; a0a = ca; }
                    else         { a1b = cb; a1a = ca; }
                }
                if (lane == 0) {
                    float4 o4 = s_ob[r]; float4 m4 = s_ms[r];
                    ob[na * 6 + 0] = o4.x; ob[na * 6 + 1] = o4.y;
                    ob[na * 6 + 2] = o4.z; ob[na * 6 + 3] = o4.w;
                    ob[na * 6 + 4] = m4.y; ob[na * 6 + 5] = m4.z;
                }
                ++na;
            }
        }
        __syncthreads();
    }
    for (int q = na * 6 + lane; q < MAXDET * 6; q += 64)
        ob[q] = 0.f;
}

extern "C" void kernel_launch(void* const* d_in, const int* in_sizes, int n_in,
                              void* d_out, int out_size, void* d_ws, size_t ws_size,
                              hipStream_t stream) {
    Ptrs p;
    for (int l = 0; l < 5; ++l) {
        p.lg[l] = (const float*)d_in[3 * l + 0];
        p.bb[l] = (const float*)d_in[3 * l + 1];
        p.ct[l] = (const float*)d_in[3 * l + 2];
    }
    const float* im_info = (const float*)d_in[15];
    float* out = (float*)d_out;
    unsigned char* w = (unsigned char*)d_ws;

    // layout (bytes):
    //   hist   @ 0        : 16*128*64*4      = 524288
    //   cnt2   @ 524288   : 4096
    //   blkcnt @ 528384   : 16*128*4         = 8192
    //   segs   @ 536576   : 16*128*768*8     = 12582912
    //   sel    @ 13119488 : 16*4096*8        = 524288
    //   cand   @ 13643776 : 16*1000*12*4     = 768000   -> total 14411776
    // No memset needed: hist/blkcnt slots written unconditionally by k_histB,
    // cnt2 zeroed by k_histB, segs read only up to blkcnt, sel/cand only up to
    // live counts.
    unsigned* hist          = (unsigned*)(w);
    unsigned* cnt2          = (unsigned*)(w + 524288);
    unsigned* blkcnt        = (unsigned*)(w + 528384);
    unsigned long long* segs = (unsigned long long*)(w + 536576);
    unsigned long long* sel = (unsigned long long*)(w + 13119488);
    float* cand             = (float*)(w + 13643776);

    k_histB<<<dim3(GH, NB), 256, 0, stream>>>(p, hist, cnt2, blkcnt, segs);
    k_filter<<<dim3(FB, NB), 256, 0, stream>>>(p, hist, blkcnt, segs, cnt2, sel);
    k_rankdec<<<dim3(16, NB), 256, 0, stream>>>(p, cnt2, sel, im_info, cand);
    k_nms<<<NB, 64, 0, stream>>>(cnt2, cand, out);
}

// Round 2
// 227.121 us; speedup vs baseline: 1.0627x; 1.0627x over previous
//
#include <hip/hip_runtime.h>
#include <math.h>

#pragma clang fp contract(off)

#define NB 16
#define NC 80
#define NTOT 17064
#define TOPK 1000
#define NBINS 8192
#define CAP 4096
#define MAXDET 100
#define CNTSTRIDE 64     // u32 stride between per-batch counters = 256 B
#define CHUNK 128        // NMS staging chunk
#define GH 128           // hist/sweep blocks per batch
#define WSEGCAP 256      // per-WAVE candidate segment (avg ~25, 10x headroom)
#define FB 16            // filter blocks per batch (GH % FB == 0)

struct Ptrs {
    const float* lg[5];
    const float* bb[5];
    const float* ct[5];
};

__device__ __forceinline__ void level_of(int n, int& l, int& hw, int& W,
                                         int& stride, int& half, int& HW) {
    if (n < 12800)      { l = 0; hw = n;         W = 128; stride = 8;   half = 4;  HW = 12800; }
    else if (n < 16000) { l = 1; hw = n - 12800; W = 64;  stride = 16;  half = 8;  HW = 3200;  }
    else if (n < 16800) { l = 2; hw = n - 16000; W = 32;  stride = 32;  half = 16; HW = 800;   }
    else if (n < 17008) { l = 3; hw = n - 16800; W = 16;  stride = 64;  half = 32; HW = 208;   }
    else                { l = 4; hw = n - 17008; W = 8;   stride = 128; half = 64; HW = 56;    }
}

// Fast HW sigmoid (v_exp_f32 + v_rcp_f32). |fast - exact| <= ~15 ulp on the
// comb product. Used for gating/binning only; keys are always exact.
__device__ __forceinline__ float fast_sig(float x) {
    float e = __expf(-x);
    return __builtin_amdgcn_rcpf(1.0f + e);
}

// ---------------- pass 1: gated 64-bin histogram + candidate store ----------
// Gate: fast comb bits >= bits(0.08)-64 (FB_LO). Gated set is IDENTICAL to the
// round-1 kernel: the old x > -2.47 pre-check is implied by bits >= FB_LO
// (comb_fast at x=-2.47 is <= ~0.0782 << 0.08-64ulp; monotone in x; exp of
// large -x saturates so comb -> 0 for OOB default x=-40). Conservative local
// bin lb = ((bits-32)>>19)-BINBASE as before; for T >= BINBASE+1 (guaranteed
// by k_filter's ok-check) {exact bin >= T} is a subset of the stored set.
// Stored entries go to per-WAVE segments indexed by a wave-uniform register
// counter (ballot + popc prefix) -> no LDS return-atomics, no serialization.
#define HG_EMIT(BITS, NN, CC, POS)                                            \
    {                                                                         \
        int lb = (int)(((BITS) - 32u) >> 19) - BINBASE;                       \
        lb = (lb < 0) ? 0 : ((lb > 63) ? 63 : lb);                            \
        atomicAdd(&whv[lb], 1u);          /* ds_add, no return: no stall */   \
        unsigned pos_ = (POS);                                                \
        if (pos_ < WSEGCAP) {                                                 \
            unsigned idx_ = (unsigned)((NN) * NC + (CC));                     \
            segw[pos_] = ((unsigned long long)(BITS) << 32) | idx_;           \
        }                                                                     \
    }

template<int HW4, int NF4, int LVOFF>
__device__ __forceinline__ void histg_level(const float* lgb, const float* ctb,
        int tid, int bx, int gx, unsigned FB_LO, int BINBASE, unsigned* whv,
        unsigned& wcnt, unsigned long long* segw, unsigned long long ltmask) {
    for (int i0 = bx * 512; i0 < NF4; i0 += gx * 512) {
        int ia = i0 + tid, ib = i0 + 256 + tid;
        bool la = ia < NF4, lb2 = ib < NF4;
        float4 va = make_float4(-40.f, -40.f, -40.f, -40.f);
        float4 vb = make_float4(-40.f, -40.f, -40.f, -40.f);
        float4 ca = make_float4(0.f, 0.f, 0.f, 0.f);
        float4 cb = make_float4(0.f, 0.f, 0.f, 0.f);
        int hwa = 0, hwb = 0, cca = 0, ccb = 0;
        if (la) {
            cca = ia / HW4; hwa = ia - cca * HW4;
            va = *(const float4*)(lgb + cca * (HW4 * 4) + hwa * 4);
            ca = *(const float4*)(ctb + hwa * 4);
        }
        if (lb2) {
            ccb = ib / HW4; hwb = ib - ccb * HW4;
            vb = *(const float4*)(lgb + ccb * (HW4 * 4) + hwb * 4);
            cb = *(const float4*)(ctb + hwb * 4);
        }
        // branchless: compute fast comb bits for all 8 slots (same formula as
        // round-1: two rcp-sigmoids, one product -> bit-identical gating)
        unsigned b0 = __float_as_uint(fast_sig(va.x) * fast_sig(ca.x));
        unsigned b1 = __float_as_uint(fast_sig(va.y) * fast_sig(ca.y));
        unsigned b2 = __float_as_uint(fast_sig(va.z) * fast_sig(ca.z));
        unsigned b3 = __float_as_uint(fast_sig(va.w) * fast_sig(ca.w));
        unsigned b4 = __float_as_uint(fast_sig(vb.x) * fast_sig(cb.x));
        unsigned b5 = __float_as_uint(fast_sig(vb.y) * fast_sig(cb.y));
        unsigned b6 = __float_as_uint(fast_sig(vb.z) * fast_sig(cb.z));
        unsigned b7 = __float_as_uint(fast_sig(vb.w) * fast_sig(cb.w));
        bool f0 = b0 >= FB_LO, f1 = b1 >= FB_LO, f2 = b2 >= FB_LO, f3 = b3 >= FB_LO;
        bool f4 = b4 >= FB_LO, f5 = b5 >= FB_LO, f6 = b6 >= FB_LO, f7 = b7 >= FB_LO;
        unsigned long long m0 = __ballot(f0), m1 = __ballot(f1);
        unsigned long long m2 = __ballot(f2), m3 = __ballot(f3);
        unsigned long long m4 = __ballot(f4), m5 = __ballot(f5);
        unsigned long long m6 = __ballot(f6), m7 = __ballot(f7);
        if (m0 | m1 | m2 | m3 | m4 | m5 | m6 | m7) {   // wave-uniform branch
            unsigned t0 = (unsigned)__popcll(m0), t1 = (unsigned)__popcll(m1);
            unsigned t2 = (unsigned)__popcll(m2), t3 = (unsigned)__popcll(m3);
            unsigned t4 = (unsigned)__popcll(m4), t5 = (unsigned)__popcll(m5);
            unsigned t6 = (unsigned)__popcll(m6), t7 = (unsigned)__popcll(m7);
            unsigned wb = wcnt;
            wcnt = wb + t0 + t1 + t2 + t3 + t4 + t5 + t6 + t7;
            int nb0a = LVOFF + hwa * 4, nb0b = LVOFF + hwb * 4;
            if (f0) HG_EMIT(b0, nb0a + 0, cca, wb + (unsigned)__popcll(m0 & ltmask))
            if (f1) HG_EMIT(b1, nb0a + 1, cca, wb + t0 + (unsigned)__popcll(m1 & ltmask))
            if (f2) HG_EMIT(b2, nb0a + 2, cca, wb + t0 + t1 + (unsigned)__popcll(m2 & ltmask))
            if (f3) HG_EMIT(b3, nb0a + 3, cca, wb + t0 + t1 + t2 + (unsigned)__popcll(m3 & ltmask))
            if (f4) HG_EMIT(b4, nb0b + 0, ccb, wb + t0 + t1 + t2 + t3 + (unsigned)__popcll(m4 & ltmask))
            if (f5) HG_EMIT(b5, nb0b + 1, ccb, wb + t0 + t1 + t2 + t3 + t4 + (unsigned)__popcll(m5 & ltmask))
            if (f6) HG_EMIT(b6, nb0b + 2, ccb, wb + t0 + t1 + t2 + t3 + t4 + t5 + (unsigned)__popcll(m6 & ltmask))
            if (f7) HG_EMIT(b7, nb0b + 3, ccb, wb + t0 + t1 + t2 + t3 + t4 + t5 + t6 + (unsigned)__popcll(m7 & ltmask))
        }
    }
}
#undef HG_EMIT

__global__ void __launch_bounds__(256) k_histB(Ptrs p, unsigned* hist, unsigned* cnt2,
                                               unsigned* wavecnt, unsigned long long* segs) {
    __shared__ unsigned wh[4][64];   // per-wave 64-bin hist, 1 KiB
    int b = blockIdx.y, tid = threadIdx.x, bx = blockIdx.x, gx = gridDim.x;
    int wv = tid >> 6, lane = tid & 63;
    if (bx == 0 && tid == 0) cnt2[(size_t)b * CNTSTRIDE] = 0;   // replaces memset
    ((unsigned*)wh)[tid] = 0;        // each wave zeroes its OWN 64 bins: no sync needed
    unsigned FB_LO = __float_as_uint(0.08f) - 64u;
    int BINBASE = (int)(__float_as_uint(0.08f) >> 19);
    unsigned* whv = wh[wv];
    unsigned long long ltmask = (1ULL << lane) - 1ULL;
    unsigned wcnt = 0;               // wave-uniform register counter
    unsigned long long* segw = segs + (((size_t)b * GH + bx) * 4 + wv) * WSEGCAP;

    histg_level<3200, 256000,     0>(p.lg[0] + (size_t)b * NC * 12800, p.ct[0] + (size_t)b * 12800, tid, bx, gx, FB_LO, BINBASE, whv, wcnt, segw, ltmask);
    histg_level< 800,  64000, 12800>(p.lg[1] + (size_t)b * NC * 3200,  p.ct[1] + (size_t)b * 3200,  tid, bx, gx, FB_LO, BINBASE, whv, wcnt, segw, ltmask);
    histg_level< 200,  16000, 16000>(p.lg[2] + (size_t)b * NC * 800,   p.ct[2] + (size_t)b * 800,   tid, bx, gx, FB_LO, BINBASE, whv, wcnt, segw, ltmask);
    histg_level<  52,   4160, 16800>(p.lg[3] + (size_t)b * NC * 208,   p.ct[3] + (size_t)b * 208,   tid, bx, gx, FB_LO, BINBASE, whv, wcnt, segw, ltmask);
    histg_level<  14,   1120, 17008>(p.lg[4] + (size_t)b * NC * 56,    p.ct[4] + (size_t)b * 56,    tid, bx, gx, FB_LO, BINBASE, whv, wcnt, segw, ltmask);

    if (lane == 0)                   // raw count (may exceed WSEGCAP)
        wavecnt[((size_t)b * GH + bx) * 4 + wv] = wcnt;
    __syncthreads();
    if (tid < 64) {                  // per-block private slot: plain store, no atomics
        unsigned s = wh[0][tid] + wh[1][tid] + wh[2][tid] + wh[3][tid];
        hist[((size_t)b * GH + bx) * 64 + tid] = s;
    }
}

// Fallback full-population conservative histogram (round-9 semantics; only
// runs if the gated ok-check fails — never for this data).
template<int HW4, int NF4>
__device__ __forceinline__ void histf_level(const float* lgb, const float* ctb,
                                            int tid, unsigned* hist) {
    for (int i0 = 0; i0 < NF4; i0 += 256) {
        int i = i0 + tid;
        if (i < NF4) {
            int c = i / HW4, hwf = i - c * HW4;
            float4 v = *(const float4*)(lgb + c * (HW4 * 4) + hwf * 4);
            if (v.x > -2.95f || v.y > -2.95f || v.z > -2.95f || v.w > -2.95f) {
                float4 cv = *(const float4*)(ctb + hwf * 4);
                float xs[4] = {v.x, v.y, v.z, v.w};
                float cs[4] = {cv.x, cv.y, cv.z, cv.w};
#pragma unroll
                for (int j = 0; j < 4; ++j) {
                    float x = xs[j];
                    if (x > -2.95f) {
                        float cls = fast_sig(x);
                        if (cls > 0.04999f) {
                            bool in = true;
                            if (cls < 0.05001f)
                                in = (1.0f / (1.0f + expf(-x))) > 0.05f;
                            if (in) {
                                float cen = fast_sig(cs[j]);
                                unsigned bits = __float_as_uint(cls * cen);
                                unsigned cb = (bits > 32u) ? bits - 32u : 0u;
                                atomicAdd(&hist[cb >> 19], 1u);
                            }
                        }
                    }
                }
            }
        }
    }
}

// ---------------- fallback full re-read compact (never taken for this data) -
#define CD_J(J, X, CT, NB0, CC, F, K)                                         \
    if ((X) > xpre) {                                                         \
        float cls = 1.0f / (1.0f + expf(-(X)));                               \
        if (cls > 0.05f) {                                                    \
            float cen = 1.0f / (1.0f + expf(-(CT)));                          \
            float comb = cls * cen;                                           \
            unsigned bits = __float_as_uint(comb);                            \
            if ((bits >> 19) >= Tb) {                                         \
                unsigned idx = (unsigned)(((NB0) + (J)) * NC + (CC));         \
                K = ((unsigned long long)bits << 32) | (0xFFFFFFFFu - idx);   \
                F = true;                                                     \
            }                                                                 \
        }                                                                     \
    }

template<int HW4, int NF4, int LVOFF>
__device__ __forceinline__ void compact_level(const float* lgb, const float* ctb,
        int tid, int lane, int bx, int gx, unsigned Tb, float xpre,
        unsigned* cntb, unsigned long long* selb, unsigned long long ltmask) {
    for (int i0 = bx * 512; i0 < NF4; i0 += gx * 512) {
        int ia = i0 + tid, ib2 = i0 + 256 + tid;
        bool la = ia < NF4, lb2 = ib2 < NF4;
        float4 va = make_float4(-9.f, -9.f, -9.f, -9.f);
        float4 vb = make_float4(-9.f, -9.f, -9.f, -9.f);
        int hwa = 0, hwb = 0, cca = 0, ccb = 0;
        if (la) {
            cca = ia / HW4; hwa = ia - cca * HW4;
            va = *(const float4*)(lgb + cca * (HW4 * 4) + hwa * 4);
        }
        if (lb2) {
            ccb = ib2 / HW4; hwb = ib2 - ccb * HW4;
            vb = *(const float4*)(lgb + ccb * (HW4 * 4) + hwb * 4);
        }
        {
            bool f0 = false, f1 = false, f2 = false, f3 = false;
            unsigned long long k0 = 0, k1 = 0, k2 = 0, k3 = 0;
            if (va.x > xpre || va.y > xpre || va.z > xpre || va.w > xpre) {
                float4 cv = *(const float4*)(ctb + hwa * 4);
                int nb0 = LVOFF + hwa * 4;
                CD_J(0, va.x, cv.x, nb0, cca, f0, k0)
                CD_J(1, va.y, cv.y, nb0, cca, f1, k1)
                CD_J(2, va.z, cv.z, nb0, cca, f2, k2)
                CD_J(3, va.w, cv.w, nb0, cca, f3, k3)
            }
            unsigned long long m0 = __ballot(f0), m1 = __ballot(f1);
            unsigned long long m2 = __ballot(f2), m3 = __ballot(f3);
            if (m0 | m1 | m2 | m3) {
                unsigned t0 = (unsigned)__popcll(m0), t1 = (unsigned)__popcll(m1);
                unsigned t2 = (unsigned)__popcll(m2), t3 = (unsigned)__popcll(m3);
                int basep = 0;
                if (lane == 0) basep = (int)atomicAdd(cntb, t0 + t1 + t2 + t3);
                basep = __shfl(basep, 0);
                if (f0) { int pos = basep + (int)__popcll(m0 & ltmask);                       if (pos < CAP) selb[pos] = k0; }
                if (f1) { int pos = basep + (int)t0 + (int)__popcll(m1 & ltmask);             if (pos < CAP) selb[pos] = k1; }
                if (f2) { int pos = basep + (int)(t0 + t1) + (int)__popcll(m2 & ltmask);      if (pos < CAP) selb[pos] = k2; }
                if (f3) { int pos = basep + (int)(t0 + t1 + t2) + (int)__popcll(m3 & ltmask); if (pos < CAP) selb[pos] = k3; }
            }
        }
        {
            bool f0 = false, f1 = false, f2 = false, f3 = false;
            unsigned long long k0 = 0, k1 = 0, k2 = 0, k3 = 0;
            if (vb.x > xpre || vb.y > xpre || vb.z > xpre || vb.w > xpre) {
                float4 cv = *(const float4*)(ctb + hwb * 4);
                int nb0 = LVOFF + hwb * 4;
                CD_J(0, vb.x, cv.x, nb0, ccb, f0, k0)
                CD_J(1, vb.y, cv.y, nb0, ccb, f1, k1)
                CD_J(2, vb.z, cv.z, nb0, ccb, f2, k2)
                CD_J(3, vb.w, cv.w, nb0, ccb, f3, k3)
            }
            unsigned long long m0 = __ballot(f0), m1 = __ballot(f1);
            unsigned long long m2 = __ballot(f2), m3 = __ballot(f3);
            if (m0 | m1 | m2 | m3) {
                unsigned t0 = (unsigned)__popcll(m0), t1 = (unsigned)__popcll(m1);
                unsigned t2 = (unsigned)__popcll(m2), t3 = (unsigned)__popcll(m3);
                int basep = 0;
                if (lane == 0) basep = (int)atomicAdd(cntb, t0 + t1 + t2 + t3);
                basep = __shfl(basep, 0);
                if (f0) { int pos = basep + (int)__popcll(m0 & ltmask);                       if (pos < CAP) selb[pos] = k0; }
                if (f1) { int pos = basep + (int)t0 + (int)__popcll(m1 & ltmask);             if (pos < CAP) selb[pos] = k1; }
                if (f2) { int pos = basep + (int)(t0 + t1) + (int)__popcll(m2 & ltmask);      if (pos < CAP) selb[pos] = k2; }
                if (f3) { int pos = basep + (int)(t0 + t1 + t2) + (int)__popcll(m3 & ltmask); if (pos < CAP) selb[pos] = k3; }
            }
        }
    }
}
#undef CD_J

__device__ __forceinline__ void run_compact(const Ptrs& p, int b, int tid, int lane,
        int bx, int gx, unsigned Tb, unsigned* cnt2, unsigned long long* sel) {
    float mthr = __uint_as_float(Tb << 19);
    float xpre = -2.95f;
    if (mthr > 1e-37f && mthr < 1.0f) {
        float lm = logf(mthr / (1.0f - mthr)) - 0.01f;
        if (lm > xpre) xpre = lm;
    }
    unsigned long long ltmask = (1ULL << lane) - 1ULL;
    unsigned* cntb = cnt2 + (size_t)b * CNTSTRIDE;
    unsigned long long* selb = sel + (size_t)b * CAP;
    compact_level<3200, 256000,     0>(p.lg[0] + (size_t)b * NC * 12800, p.ct[0] + (size_t)b * 12800, tid, lane, bx, gx, Tb, xpre, cntb, selb, ltmask);
    compact_level< 800,  64000, 12800>(p.lg[1] + (size_t)b * NC * 3200,  p.ct[1] + (size_t)b * 3200,  tid, lane, bx, gx, Tb, xpre, cntb, selb, ltmask);
    compact_level< 200,  16000, 16000>(p.lg[2] + (size_t)b * NC * 800,   p.ct[2] + (size_t)b * 800,   tid, lane, bx, gx, Tb, xpre, cntb, selb, ltmask);
    compact_level<  52,   4160, 16800>(p.lg[3] + (size_t)b * NC * 208,   p.ct[3] + (size_t)b * 208,   tid, lane, bx, gx, Tb, xpre, cntb, selb, ltmask);
    compact_level<  14,   1120, 17008>(p.lg[4] + (size_t)b * NC * 56,    p.ct[4] + (size_t)b * 56,    tid, lane, bx, gx, Tb, xpre, cntb, selb, ltmask);
}

// ---------------- pass 2: threshold + filter stored candidates --------------
__global__ void __launch_bounds__(256) k_filter(Ptrs p, const unsigned* hist,
        const unsigned* wavecnt, const unsigned long long* segs,
        unsigned* cnt2, unsigned long long* sel) {
    __shared__ unsigned part[4][64];
    __shared__ unsigned red[64];
    __shared__ unsigned fullh[NBINS];   // fallback only (32 KiB)
    __shared__ int s_T, s_ok;
    __shared__ unsigned s_ovf;
    int b = blockIdx.y, tid = threadIdx.x, bx = blockIdx.x;
    int bin = tid & 63, grp = tid >> 6, lane = tid & 63, wv = tid >> 6;
    int BINBASE = (int)(__float_as_uint(0.08f) >> 19);

    unsigned s = 0;
    for (int blk = grp; blk < GH; blk += 4)
        s += hist[((size_t)b * GH + blk) * 64 + bin];   // coalesced per 64-group
    part[grp][bin] = s;
    if (tid == 0) s_ovf = 0;
    __syncthreads();
    if (tid < 64) red[tid] = part[0][tid] + part[1][tid] + part[2][tid] + part[3][tid];
    unsigned ov = 0;
    for (int i = tid; i < GH * 4; i += 256)
        ov |= (wavecnt[(size_t)b * GH * 4 + i] > WSEGCAP) ? 1u : 0u;
    if (ov) atomicOr(&s_ovf, 1u);
    __syncthreads();
    if (tid == 0) {
        unsigned suf1 = 0;
        for (int i = 1; i < 64; ++i) suf1 += red[i];
        unsigned run = 0; int Tl = 0;
        for (int i = 63; i >= 1; --i) {
            run += red[i];
            if (run >= TOPK) { Tl = i; break; }
        }
        s_ok = (suf1 >= TOPK);
        s_T = Tl + BINBASE;
    }
    __syncthreads();

    if (s_ok && !s_ovf) {
        unsigned Tb = (unsigned)s_T;
        unsigned FLO = (Tb << 19) - 64u;    // T >= BINBASE+1 => no underflow
        unsigned* cntb = cnt2 + (size_t)b * CNTSTRIDE;
        unsigned long long* selb = sel + (size_t)b * CAP;
        unsigned long long ltmask = (1ULL << lane) - 1ULL;
        for (int sg = bx * 4 + wv; sg < GH * 4; sg += FB * 4) {   // one seg per wave
            unsigned cs = wavecnt[(size_t)b * GH * 4 + sg];
            if (cs > WSEGCAP) cs = WSEGCAP;
            const unsigned long long* sp = segs + ((size_t)b * GH * 4 + sg) * WSEGCAP;
            for (unsigned e0 = 0; e0 < cs; e0 += 64) {
                unsigned e = e0 + (unsigned)lane;
                bool take = false;
                unsigned long long key = 0;
                if (e < cs) {
                    unsigned long long kk = sp[e];
                    if ((unsigned)(kk >> 32) >= FLO) {
                        unsigned idx = (unsigned)kk;
                        int n = (int)(idx / NC), c = (int)(idx - (unsigned)n * NC);
                        int l, hw, W, stride, half, HW;
                        level_of(n, l, hw, W, stride, half, HW);
                        float x   = p.lg[l][(size_t)b * NC * HW + (size_t)c * HW + hw];
                        float ctv = p.ct[l][(size_t)b * HW + hw];
                        float cls = 1.0f / (1.0f + expf(-x));
                        if (cls > 0.05f) {           // auto-true when bin>=T; kept for safety
                            float cen = 1.0f / (1.0f + expf(-ctv));
                            unsigned bits = __float_as_uint(cls * cen);
                            if ((bits >> 19) >= Tb) {
                                key = ((unsigned long long)bits << 32) | (0xFFFFFFFFu - idx);
                                take = true;
                            }
                        }
                    }
                }
                unsigned long long m = __ballot(take);
                if (m) {
                    unsigned tot = (unsigned)__popcll(m);
                    int basep = 0;
                    if (lane == 0) basep = (int)atomicAdd(cntb, tot);
                    basep = __shfl(basep, 0);
                    if (take) {
                        int pos = basep + (int)__popcll(m & ltmask);
                        if (pos < CAP) selb[pos] = key;
                    }
                }
            }
        }
        return;
    }

    if (!s_ok) {                        // never taken for this data
        if (bx != 0) return;
        for (int i = tid; i < NBINS; i += 256) fullh[i] = 0;
        __syncthreads();
        histf_level<3200, 256000>(p.lg[0] + (size_t)b * NC * 12800, p.ct[0] + (size_t)b * 12800, tid, fullh);
        histf_level< 800,  64000>(p.lg[1] + (size_t)b * NC * 3200,  p.ct[1] + (size_t)b * 3200,  tid, fullh);
        histf_level< 200,  16000>(p.lg[2] + (size_t)b * NC * 800,   p.ct[2] + (size_t)b * 800,   tid, fullh);
        histf_level<  52,   4160>(p.lg[3] + (size_t)b * NC * 208,   p.ct[3] + (size_t)b * 208,   tid, fullh);
        histf_level<  14,   1120>(p.lg[4] + (size_t)b * NC * 56,    p.ct[4] + (size_t)b * 56,    tid, fullh);
        __syncthreads();
        if (tid == 0) {
            unsigned run = 0; int Tf = 0;
            for (int i = NBINS - 1; i >= 0; --i) {
                run += fullh[i];
                if (run >= TOPK) { Tf = i; break; }
            }
            s_T = Tf;
        }
        __syncthreads();
        run_compact(p, b, tid, lane, 0, 1, (unsigned)s_T, cnt2, sel);
        return;
    }

    // ok but segment overflow: T valid, full re-read with FB blocks (never taken)
    run_compact(p, b, tid, lane, bx, FB, (unsigned)s_T, cnt2, sel);
}

// ---------------- rank + decode (distributed across CUs) --------------------
__global__ void __launch_bounds__(256) k_rankdec(Ptrs p, const unsigned* cnt,
                                                 const unsigned long long* sel,
                                                 const float* im_info, float* cand) {
    __shared__ __align__(16) unsigned long long keys[CAP];
    int b = blockIdx.y, tid = threadIdx.x;
    unsigned M = cnt[(size_t)b * CNTSTRIDE];
    if (M > CAP) M = CAP;
    int s0 = blockIdx.x * 256;
    if (s0 >= (int)M) return;
    int Mpad = (int)((M + 1u) & ~1u);
    for (int i = tid; i < Mpad; i += 256)
        keys[i] = (i < (int)M) ? sel[(size_t)b * CAP + i] : 0ULL;
    __syncthreads();

    int s = s0 + tid;
    if (s >= (int)M) return;
    unsigned long long k = keys[s];
    int rank = 0;
    for (int j = 0; j < Mpad; j += 2) {
        ulonglong2 kk = *(const ulonglong2*)&keys[j];   // wave-broadcast b128
        rank += (kk.x > k) ? 1 : 0;
        rank += (kk.y > k) ? 1 : 0;
    }
    if (rank >= TOPK) return;

    float Him = im_info[b * 2 + 0], Wim = im_info[b * 2 + 1];
    float xmax = Wim - 1.0f, ymax = Him - 1.0f;
    unsigned sb = (unsigned)(k >> 32);
    unsigned idx = 0xFFFFFFFFu - (unsigned)(k & 0xFFFFFFFFu);
    float val = __uint_as_float(sb);
    int n = idx / NC, c = idx - n * NC;
    int l, hw, W, stride, half, HW;
    level_of(n, l, hw, W, stride, half, HW);
    int wx = hw % W, hy = hw / W;
    float locx = (float)(wx * stride + half);
    float locy = (float)(hy * stride + half);
    const float* bb = p.bb[l] + (size_t)b * 4 * HW + hw;
    float r0 = bb[0], r1 = bb[(size_t)HW], r2 = bb[(size_t)2 * HW], r3 = bb[(size_t)3 * HW];
    float x1 = locx - r0, y1 = locy - r1, x2 = locx + r2, y2 = locy + r3;
    x1 = fminf(fmaxf(x1, 0.f), xmax);
    y1 = fminf(fmaxf(y1, 0.f), ymax);
    x2 = fminf(fmaxf(x2, 0.f), xmax);
    y2 = fminf(fmaxf(y2, 0.f), ymax);
    float scv = sqrtf(val + 1e-12f);
    float off = (float)c * 10000.0f;
    float a0 = x1 + off, a1 = y1 + off, a2 = x2 + off, a3 = y2 + off;
    float area = fmaxf(a2 - a0, 0.f) * fmaxf(a3 - a1, 0.f);
    float* dst = cand + ((size_t)b * TOPK + rank) * 12;
    *(float4*)(dst + 0) = make_float4(x1, y1, x2, y2);
    *(float4*)(dst + 4) = make_float4(a0, a1, a2, a3);
    *(float4*)(dst + 8) = make_float4(area, scv, (float)c, 0.f);
}

// ---------------- scan-NMS (one wave per batch) -----------------------------
__global__ void __launch_bounds__(64) k_nms(const unsigned* cnt, const float* cand,
                                            float* out) {
    __shared__ float4 s_ob[CHUNK], s_nb[CHUNK], s_ms[CHUNK];
    int b = blockIdx.x, lane = threadIdx.x;
    unsigned M = cnt[(size_t)b * CNTSTRIDE];
    if (M > CAP) M = CAP;
    int ncand = (int)M < TOPK ? (int)M : TOPK;
    const float* src = cand + (size_t)b * TOPK * 12;
    float* ob = out + (size_t)b * MAXDET * 6;

    int na = 0;
    float4 a0b = make_float4(0.f, 0.f, 0.f, 0.f);
    float4 a1b = make_float4(0.f, 0.f, 0.f, 0.f);
    float a0a = 0.f, a1a = 0.f;

    for (int base = 0; base < ncand && na < MAXDET; base += CHUNK) {
        int cn = ncand - base; if (cn > CHUNK) cn = CHUNK;
        for (int cidx = lane; cidx < cn; cidx += 64) {
            const float* s = src + (size_t)(base + cidx) * 12;
            s_ob[cidx] = *(const float4*)(s + 0);
            s_nb[cidx] = *(const float4*)(s + 4);
            s_ms[cidx] = *(const float4*)(s + 8);
        }
        __syncthreads();
        for (int r = 0; r < cn && na < MAXDET; ++r) {
            float4 cb = s_nb[r];
            float ca = s_ms[r].x;
            bool sup = false;
            if (lane < na) {
                float xx1 = fmaxf(a0b.x, cb.x);
                float yy1 = fmaxf(a0b.y, cb.y);
                float xx2 = fminf(a0b.z, cb.z);
                float yy2 = fminf(a0b.w, cb.w);
                float inter = fmaxf(xx2 - xx1, 0.f) * fmaxf(yy2 - yy1, 0.f);
                float iou = inter / (((a0a + ca) - inter) + 1e-9f);
                sup = (iou >= 0.6f);
            }
            if (lane + 64 < na) {
                float xx1 = fmaxf(a1b.x, cb.x);
                float yy1 = fmaxf(a1b.y, cb.y);
                float xx2 = fminf(a1b.z, cb.z);
                float yy2 = fminf(a1b.w, cb.w);
                float inter = fmaxf(xx2 - xx1, 0.f) * fmaxf(yy2 - yy1, 0.f);
                float iou = inter / (((a1a + ca) - inter) + 1e-9f);
                sup |= (iou >= 0.6f);
            }
            if (__ballot(sup) == 0ULL) {
                if (lane == (na & 63)) {
                    if (na < 64) { a0b = cb; a0a = ca; }
                    else         { a1b = cb; a1a = ca; }
                }
                if (lane == 0) {
                    float4 o4 = s_ob[r]; float4 m4 = s_ms[r];
                    ob[na * 6 + 0] = o4.x; ob[na * 6 + 1] = o4.y;
                    ob[na * 6 + 2] = o4.z; ob[na * 6 + 3] = o4.w;
                    ob[na * 6 + 4] = m4.y; ob[na * 6 + 5] = m4.z;
                }
                ++na;
            }
        }
        __syncthreads();
    }
    for (int q = na * 6 + lane; q < MAXDET * 6; q += 64)
        ob[q] = 0.f;
}

extern "C" void kernel_launch(void* const* d_in, const int* in_sizes, int n_in,
                              void* d_out, int out_size, void* d_ws, size_t ws_size,
                              hipStream_t stream) {
    Ptrs p;
    for (int l = 0; l < 5; ++l) {
        p.lg[l] = (const float*)d_in[3 * l + 0];
        p.bb[l] = (const float*)d_in[3 * l + 1];
        p.ct[l] = (const float*)d_in[3 * l + 2];
    }
    const float* im_info = (const float*)d_in[15];
    float* out = (float*)d_out;
    unsigned char* w = (unsigned char*)d_ws;

    // layout (bytes):
    //   hist    @ 0        : 16*128*64*4       = 524288
    //   cnt2    @ 524288   : 4096
    //   wavecnt @ 528384   : 16*512*4          = 32768
    //   segs    @ 561152   : 16*512*256*8      = 16777216
    //   sel     @ 17338368 : 16*4096*8         = 524288
    //   cand    @ 17862656 : 16*1000*12*4      = 768000   -> total 18630656
    // No memset needed: hist/wavecnt slots written unconditionally by k_histB,
    // cnt2 zeroed by k_histB, segs read only up to wavecnt, sel/cand only up
    // to live counts.
    unsigned* hist           = (unsigned*)(w);
    unsigned* cnt2           = (unsigned*)(w + 524288);
    unsigned* wavecnt        = (unsigned*)(w + 528384);
    unsigned long long* segs = (unsigned long long*)(w + 561152);
    unsigned long long* sel  = (unsigned long long*)(w + 17338368);
    float* cand              = (float*)(w + 17862656);

    k_histB<<<dim3(GH, NB), 256, 0, stream>>>(p, hist, cnt2, wavecnt, segs);
    k_filter<<<dim3(FB, NB), 256, 0, stream>>>(p, hist, wavecnt, segs, cnt2, sel);
    k_rankdec<<<dim3(16, NB), 256, 0, stream>>>(p, cnt2, sel, im_info, cand);
    k_nms<<<NB, 64, 0, stream>>>(cnt2, cand, out);
}